// Round 1
// baseline (302.348 us; speedup 1.0000x reference)
//
#include <hip/hip_runtime.h>

typedef __bf16 bf16x8 __attribute__((ext_vector_type(8)));
typedef float f32x4 __attribute__((ext_vector_type(4)));
typedef unsigned short u16;

#define HDIM 768
#define NHEADS 12
#define SEQ 1024
#define NBATCH 4
#define ROWS 4096      // B*T
#define QKV3 2304
#define INTERDIM 3072

__device__ __forceinline__ u16 f2bf(float f) {
  union { float f; unsigned int u; } v; v.f = f;
  unsigned int r = v.u + 0x7fffu + ((v.u >> 16) & 1u);
  return (u16)(r >> 16);
}

// ---------------- f32 -> bf16 copy (vectorized x4) ----------------
__global__ void k_f32_to_bf16(const float* __restrict__ in, u16* __restrict__ out, int n4) {
  int i = blockIdx.x * 256 + threadIdx.x;
  if (i < n4) {
    float4 f = reinterpret_cast<const float4*>(in)[i];
    ushort4 o;
    o.x = f2bf(f.x); o.y = f2bf(f.y); o.z = f2bf(f.z); o.w = f2bf(f.w);
    reinterpret_cast<ushort4*>(out)[i] = o;
  }
}

// ---------------- f32 [K][N] -> bf16 [N][K] transpose ----------------
__global__ void k_transpose_bf16(const float* __restrict__ in, u16* __restrict__ out,
                                 int K, int N) {
  __shared__ float tile[32][33];
  int tx = threadIdx.x & 31, ty = threadIdx.x >> 5;
  int n0 = blockIdx.x * 32, k0 = blockIdx.y * 32;
#pragma unroll
  for (int i = 0; i < 32; i += 8)
    tile[ty + i][tx] = in[(size_t)(k0 + ty + i) * N + n0 + tx];
  __syncthreads();
#pragma unroll
  for (int i = 0; i < 32; i += 8)
    out[(size_t)(n0 + ty + i) * K + k0 + tx] = f2bf(tile[tx][ty + i]);
}

// ---------------- bf16 MFMA GEMM: C = A[M][K] * Bt[N][K]^T ----------------
// 128x128 tile, BK=32, 4 waves (2x2), each wave 64x64 = 4x4 frags of 16x16x32.
// modes: 0: obf=bf16(C)                        (qkv)
//        1: t=e1[idx]+0.2*C+e2[col]; of32=t, obf=bf16(t)   (w_o + residual)
//        2: t=relu(C+e1[col]); obf=bf16(t)     (ffn1)
//        3: of32 = C+e1[col]+e2[idx]+e3[col]   (ffn2 + residual, final out)
#define LDK 56  // padded LDS K-stride (elems): 112B = 7*16B, 16B-aligned rows

__global__ __launch_bounds__(256) void k_gemm(
    const u16* __restrict__ A, const u16* __restrict__ Bt,
    int M, int N, int K, int mode,
    u16* __restrict__ obf, float* __restrict__ of32,
    const float* __restrict__ e1, const float* __restrict__ e2,
    const float* __restrict__ e3) {
  __shared__ u16 As[128 * LDK];
  __shared__ u16 Bs[128 * LDK];
  int tid = threadIdx.x;
  int lane = tid & 63, wid = tid >> 6;
  int wr = wid >> 1, wc = wid & 1;
  int m0 = blockIdx.y * 128, n0 = blockIdx.x * 128;
  int fr = lane & 15, fg = lane >> 4, fk = fg * 8;

  f32x4 acc[4][4] = {};

  int sr = tid >> 1;            // staging row 0..127
  int sk = (tid & 1) * 16;      // staging k-half
  const u16* Ag = A + (size_t)(m0 + sr) * K + sk;
  const u16* Bg = Bt + (size_t)(n0 + sr) * K + sk;
  u16* Asw = &As[sr * LDK + sk];
  u16* Bsw = &Bs[sr * LDK + sk];

  for (int kt = 0; kt < K; kt += 32) {
    int4 a0 = *reinterpret_cast<const int4*>(Ag + kt);
    int4 a1 = *reinterpret_cast<const int4*>(Ag + kt + 8);
    int4 b0 = *reinterpret_cast<const int4*>(Bg + kt);
    int4 b1 = *reinterpret_cast<const int4*>(Bg + kt + 8);
    __syncthreads();
    *reinterpret_cast<int4*>(Asw) = a0;
    *reinterpret_cast<int4*>(Asw + 8) = a1;
    *reinterpret_cast<int4*>(Bsw) = b0;
    *reinterpret_cast<int4*>(Bsw + 8) = b1;
    __syncthreads();

    bf16x8 af[4], bfv[4];
#pragma unroll
    for (int mi = 0; mi < 4; mi++)
      af[mi] = *reinterpret_cast<const bf16x8*>(&As[(wr * 64 + mi * 16 + fr) * LDK + fk]);
#pragma unroll
    for (int ni = 0; ni < 4; ni++)
      bfv[ni] = *reinterpret_cast<const bf16x8*>(&Bs[(wc * 64 + ni * 16 + fr) * LDK + fk]);
#pragma unroll
    for (int mi = 0; mi < 4; mi++)
#pragma unroll
      for (int ni = 0; ni < 4; ni++)
        acc[mi][ni] = __builtin_amdgcn_mfma_f32_16x16x32_bf16(af[mi], bfv[ni], acc[mi][ni], 0, 0, 0);
  }

#pragma unroll
  for (int mi = 0; mi < 4; mi++) {
#pragma unroll
    for (int ni = 0; ni < 4; ni++) {
#pragma unroll
      for (int i = 0; i < 4; i++) {
        int row = m0 + wr * 64 + mi * 16 + fg * 4 + i;
        int col = n0 + wc * 64 + ni * 16 + fr;
        float v = acc[mi][ni][i];
        size_t idx = (size_t)row * N + col;
        if (mode == 0) {
          obf[idx] = f2bf(v);
        } else if (mode == 1) {
          float t = e1[idx] + 0.2f * v + e2[col];
          of32[idx] = t;
          obf[idx] = f2bf(t);
        } else if (mode == 2) {
          float t = v + e1[col];
          t = t > 0.f ? t : 0.f;
          obf[idx] = f2bf(t);
        } else {
          of32[idx] = v + e1[col] + e2[idx] + e3[col];
        }
      }
    }
  }
}

// ---------------- fused 2quad attention ----------------
// grid (SEQ/64, HEADS, B), 256 threads = 4 waves, wave w owns q rows t0..t0+15.
// out[t][d] = sum_s w_ts * v_s / (sum_s w_ts + eps), w_ts = (q.k * rs)^2 * mask_s
__global__ __launch_bounds__(256) void k_attn(
    const u16* __restrict__ qkv, const float* __restrict__ mask,
    const float* __restrict__ tau, u16* __restrict__ outp) {
  __shared__ u16 Ks[64 * 72];
  __shared__ u16 Vt[64 * 72];
  __shared__ u16 Ps[4][16 * 72];
  int tid = threadIdx.x, lane = tid & 63, w = tid >> 6;
  int h = blockIdx.y, b = blockIdx.z;
  int fr = lane & 15, fg = lane >> 4, fk = fg * 8;
  int rb = b * SEQ;
  float rs = 1.0f / (8.0f * tau[h]);

  int t0 = blockIdx.x * 64 + w * 16;
  const u16* qrow = qkv + (size_t)(rb + t0 + fr) * QKV3 + h * 64;
  bf16x8 aq0 = *reinterpret_cast<const bf16x8*>(qrow + fk);
  bf16x8 aq1 = *reinterpret_cast<const bf16x8*>(qrow + 32 + fk);

  f32x4 acco[4] = {};
  float den[4] = {0.f, 0.f, 0.f, 0.f};

  int sr = tid >> 2, sq = (tid & 3) * 16;  // stage: row 0..63, 16-d chunk
  const u16* kg = qkv + (size_t)(rb + sr) * QKV3 + HDIM + h * 64 + sq;
  const u16* vg = qkv + (size_t)(rb + sr) * QKV3 + 2 * HDIM + h * 64 + sq;

  for (int st = 0; st < SEQ; st += 64) {
    int4 kv0 = *reinterpret_cast<const int4*>(kg + (size_t)st * QKV3);
    int4 kv1 = *reinterpret_cast<const int4*>(kg + (size_t)st * QKV3 + 8);
    int4 vv0 = *reinterpret_cast<const int4*>(vg + (size_t)st * QKV3);
    int4 vv1 = *reinterpret_cast<const int4*>(vg + (size_t)st * QKV3 + 8);
    __syncthreads();
    *reinterpret_cast<int4*>(&Ks[sr * 72 + sq]) = kv0;
    *reinterpret_cast<int4*>(&Ks[sr * 72 + sq + 8]) = kv1;
    const u16* vp0 = reinterpret_cast<const u16*>(&vv0);
    const u16* vp1 = reinterpret_cast<const u16*>(&vv1);
#pragma unroll
    for (int i = 0; i < 8; i++) Vt[(sq + i) * 72 + sr] = vp0[i];
#pragma unroll
    for (int i = 0; i < 8; i++) Vt[(sq + 8 + i) * 72 + sr] = vp1[i];
    __syncthreads();

    // scores + weights + den + P staging
#pragma unroll
    for (int sf = 0; sf < 4; sf++) {
      bf16x8 bk0 = *reinterpret_cast<const bf16x8*>(&Ks[(sf * 16 + fr) * 72 + fk]);
      bf16x8 bk1 = *reinterpret_cast<const bf16x8*>(&Ks[(sf * 16 + fr) * 72 + 32 + fk]);
      f32x4 s = {};
      s = __builtin_amdgcn_mfma_f32_16x16x32_bf16(aq0, bk0, s, 0, 0, 0);
      s = __builtin_amdgcn_mfma_f32_16x16x32_bf16(aq1, bk1, s, 0, 0, 0);
      float mval = mask[b * SEQ + st + sf * 16 + fr];
#pragma unroll
      for (int i = 0; i < 4; i++) {
        float sv = s[i] * rs;
        float wv = sv * sv * mval;
        Ps[w][(fg * 4 + i) * 72 + sf * 16 + fr] = f2bf(wv);
        wv += __shfl_xor(wv, 1);
        wv += __shfl_xor(wv, 2);
        wv += __shfl_xor(wv, 4);
        wv += __shfl_xor(wv, 8);
        den[i] += wv;
      }
    }
    // PV
    bf16x8 ap0 = *reinterpret_cast<const bf16x8*>(&Ps[w][fr * 72 + fk]);
    bf16x8 ap1 = *reinterpret_cast<const bf16x8*>(&Ps[w][fr * 72 + 32 + fk]);
#pragma unroll
    for (int df = 0; df < 4; df++) {
      bf16x8 bv0 = *reinterpret_cast<const bf16x8*>(&Vt[(df * 16 + fr) * 72 + fk]);
      bf16x8 bv1 = *reinterpret_cast<const bf16x8*>(&Vt[(df * 16 + fr) * 72 + 32 + fk]);
      acco[df] = __builtin_amdgcn_mfma_f32_16x16x32_bf16(ap0, bv0, acco[df], 0, 0, 0);
      acco[df] = __builtin_amdgcn_mfma_f32_16x16x32_bf16(ap1, bv1, acco[df], 0, 0, 0);
    }
  }

#pragma unroll
  for (int df = 0; df < 4; df++)
#pragma unroll
    for (int i = 0; i < 4; i++) {
      int t = t0 + fg * 4 + i;
      int col = h * 64 + df * 16 + fr;
      float o = acco[df][i] / (den[i] + 1e-6f);
      outp[(size_t)(rb + t) * HDIM + col] = f2bf(o);
    }
}

extern "C" void kernel_launch(void* const* d_in, const int* in_sizes, int n_in,
                              void* d_out, int out_size, void* d_ws, size_t ws_size,
                              hipStream_t stream) {
  const float* x     = (const float*)d_in[0];
  const float* mask  = (const float*)d_in[1];
  const float* w_qkv = (const float*)d_in[2];
  const float* w_o   = (const float*)d_in[3];
  const float* tau   = (const float*)d_in[4];
  const float* w1    = (const float*)d_in[5];
  const float* b1    = (const float*)d_in[6];
  const float* w2    = (const float*)d_in[7];
  const float* b2    = (const float*)d_in[8];
  const float* nb1   = (const float*)d_in[9];
  const float* nb2   = (const float*)d_in[10];
  float* out = (float*)d_out;

  char* p = (char*)d_ws;
  u16* xb    = (u16*)p; p += (size_t)ROWS * HDIM * 2;
  u16* wqkvT = (u16*)p; p += (size_t)QKV3 * HDIM * 2;
  u16* woT   = (u16*)p; p += (size_t)HDIM * HDIM * 2;
  u16* w1T   = (u16*)p; p += (size_t)INTERDIM * HDIM * 2;
  u16* w2T   = (u16*)p; p += (size_t)HDIM * INTERDIM * 2;
  u16* qkvb  = (u16*)p; p += (size_t)ROWS * QKV3 * 2;
  u16* attnb = (u16*)p; p += (size_t)ROWS * HDIM * 2;
  float* x1f = (float*)p; p += (size_t)ROWS * HDIM * 4;
  u16* x1b   = (u16*)p; p += (size_t)ROWS * HDIM * 2;
  u16* hb    = (u16*)p; p += (size_t)ROWS * INTERDIM * 2;
  (void)ws_size; (void)in_sizes; (void)n_in; (void)out_size;

  // pre-pass: conversions + weight transposes
  k_f32_to_bf16<<<(ROWS * HDIM / 4 + 255) / 256, 256, 0, stream>>>(x, xb, ROWS * HDIM / 4);
  k_transpose_bf16<<<dim3(QKV3 / 32, HDIM / 32), 256, 0, stream>>>(w_qkv, wqkvT, HDIM, QKV3);
  k_transpose_bf16<<<dim3(HDIM / 32, HDIM / 32), 256, 0, stream>>>(w_o, woT, HDIM, HDIM);
  k_transpose_bf16<<<dim3(INTERDIM / 32, HDIM / 32), 256, 0, stream>>>(w1, w1T, HDIM, INTERDIM);
  k_transpose_bf16<<<dim3(HDIM / 32, INTERDIM / 32), 256, 0, stream>>>(w2, w2T, INTERDIM, HDIM);

  // qkv = x @ w_qkv  -> bf16
  k_gemm<<<dim3(QKV3 / 128, ROWS / 128), 256, 0, stream>>>(
      xb, wqkvT, ROWS, QKV3, HDIM, 0, qkvb, nullptr, nullptr, nullptr, nullptr);
  // attention
  k_attn<<<dim3(SEQ / 64, NHEADS, NBATCH), 256, 0, stream>>>(qkvb, mask, tau, attnb);
  // x1 = x + 0.2*(attn @ w_o) + nb1
  k_gemm<<<dim3(HDIM / 128, ROWS / 128), 256, 0, stream>>>(
      attnb, woT, ROWS, HDIM, HDIM, 1, x1b, x1f, x, nb1, nullptr);
  // h = relu(x1 @ w1 + b1)
  k_gemm<<<dim3(INTERDIM / 128, ROWS / 128), 256, 0, stream>>>(
      x1b, w1T, ROWS, INTERDIM, HDIM, 2, hb, nullptr, b1, nullptr, nullptr);
  // out = x1 + (h @ w2 + b2) + nb2
  k_gemm<<<dim3(HDIM / 128, ROWS / 128), 256, 0, stream>>>(
      hb, w2T, ROWS, HDIM, INTERDIM, 3, nullptr, out, b2, x1f, nb2);
}

// Round 2
// 223.420 us; speedup vs baseline: 1.3533x; 1.3533x over previous
//
#include <hip/hip_runtime.h>

typedef __bf16 bf16x8 __attribute__((ext_vector_type(8)));
typedef float f32x4 __attribute__((ext_vector_type(4)));
typedef unsigned short u16;

#define HDIM 768
#define NHEADS 12
#define SEQ 1024
#define NBATCH 4
#define ROWS 4096      // B*T
#define QKV3 2304
#define INTERDIM 3072

__device__ __forceinline__ u16 f2bf(float f) {
  union { float f; unsigned int u; } v; v.f = f;
  unsigned int r = v.u + 0x7fffu + ((v.u >> 16) & 1u);
  return (u16)(r >> 16);
}

// async global->LDS, 16B per lane. LDS dest is wave-uniform base + lane*16.
__device__ __forceinline__ void gload16(const u16* g, u16* l) {
  __builtin_amdgcn_global_load_lds(
      (const __attribute__((address_space(1))) void*)g,
      (__attribute__((address_space(3))) void*)l, 16, 0, 0);
}

// ---------------- f32 -> bf16 copy (vectorized x4) ----------------
__global__ void k_f32_to_bf16(const float* __restrict__ in, u16* __restrict__ out, int n4) {
  int i = blockIdx.x * 256 + threadIdx.x;
  if (i < n4) {
    float4 f = reinterpret_cast<const float4*>(in)[i];
    ushort4 o;
    o.x = f2bf(f.x); o.y = f2bf(f.y); o.z = f2bf(f.z); o.w = f2bf(f.w);
    reinterpret_cast<ushort4*>(out)[i] = o;
  }
}

// ---------------- f32 [K][N] -> bf16 [N][K] transpose ----------------
__global__ void k_transpose_bf16(const float* __restrict__ in, u16* __restrict__ out,
                                 int K, int N) {
  __shared__ float tile[32][33];
  int tx = threadIdx.x & 31, ty = threadIdx.x >> 5;
  int n0 = blockIdx.x * 32, k0 = blockIdx.y * 32;
#pragma unroll
  for (int i = 0; i < 32; i += 8)
    tile[ty + i][tx] = in[(size_t)(k0 + ty + i) * N + n0 + tx];
  __syncthreads();
#pragma unroll
  for (int i = 0; i < 32; i += 8)
    out[(size_t)(n0 + ty + i) * K + k0 + tx] = f2bf(tile[tx][ty + i]);
}

// ---------------- bf16 MFMA GEMM: C = A[M][K] * Bt[N][K]^T ----------------
// m97 structure: BM=128, BK=32, linear LDS, global_load_lds width-16 staging.
// BN=128: 4 waves 2x2, wave tile 64x64 (4x4 frags).
// BN=64 : 4 waves 4x1, wave tile 32x64 (2x4 frags).
// modes: 0: obf=bf16(C)                                   (qkv)
//        1: t=e1[idx]+0.2*C+e2[col]; of32=t, obf=bf16(t)  (w_o + residual)
//        2: t=relu(C+e1[col]); obf=bf16(t)                (ffn1)
//        3: of32[z*M*N+idx] = C                           (ffn2 split-K partial)
template<int BN, int MODE>
__global__ __launch_bounds__(256) void k_gemm(
    const u16* __restrict__ A, const u16* __restrict__ Bt,
    int M, int N, int K, int ksplit,
    u16* __restrict__ obf, float* __restrict__ of32,
    const float* __restrict__ e1, const float* __restrict__ e2) {
  constexpr int BM = 128, BK = 32;
  constexpr int WC = (BN == 128) ? 2 : 1;   // waves across N
  constexpr int WR = 4 / WC;                // waves across M
  constexpr int WM = BM / WR;               // wave tile rows
  constexpr int WN = BN / WC;               // wave tile cols
  constexpr int MFR = WM / 16;
  constexpr int NFR = WN / 16;
  __shared__ u16 As[BM * BK];
  __shared__ u16 Bs[BN * BK];
  int tid = threadIdx.x, lane = tid & 63, wid = tid >> 6;
  int wr = wid / WC, wc = wid % WC;
  int m0 = blockIdx.y * BM, n0 = blockIdx.x * BN;
  int Kc = K / ksplit, k0 = blockIdx.z * Kc;
  int fr = lane & 15, fg = lane >> 4, fk = fg * 8;

  f32x4 acc[MFR][NFR] = {};

  // staging geometry: one issue = 256 lanes * 8 elems = 2048 elems (64 rows x 32)
  int e = tid * 8;
  int r = e >> 5, c = e & 31;
  const u16* Ag = A + (size_t)(m0 + r) * K + k0 + c;
  const u16* Bg = Bt + (size_t)(n0 + r) * K + k0 + c;
  u16* Asl = &As[wid * 512];   // wave-uniform LDS base (lane adds *16B in HW)
  u16* Bsl = &Bs[wid * 512];

  for (int kt = 0; kt < Kc; kt += BK) {
    __syncthreads();
    gload16(Ag + kt, Asl);
    gload16(Ag + kt + (size_t)64 * K, Asl + 2048);
    gload16(Bg + kt, Bsl);
    if (BN == 128) gload16(Bg + kt + (size_t)64 * K, Bsl + 2048);
    __syncthreads();  // compiler drains vmcnt(0) here -> LDS tile ready

    bf16x8 af[MFR], bfv[NFR];
#pragma unroll
    for (int mi = 0; mi < MFR; mi++)
      af[mi] = *reinterpret_cast<const bf16x8*>(&As[(wr * WM + mi * 16 + fr) * BK + fk]);
#pragma unroll
    for (int ni = 0; ni < NFR; ni++)
      bfv[ni] = *reinterpret_cast<const bf16x8*>(&Bs[(wc * WN + ni * 16 + fr) * BK + fk]);
#pragma unroll
    for (int mi = 0; mi < MFR; mi++)
#pragma unroll
      for (int ni = 0; ni < NFR; ni++)
        acc[mi][ni] = __builtin_amdgcn_mfma_f32_16x16x32_bf16(af[mi], bfv[ni], acc[mi][ni], 0, 0, 0);
  }

  float* part = (MODE == 3) ? of32 + (size_t)blockIdx.z * ((size_t)M * N) : of32;
#pragma unroll
  for (int mi = 0; mi < MFR; mi++) {
#pragma unroll
    for (int ni = 0; ni < NFR; ni++) {
#pragma unroll
      for (int i = 0; i < 4; i++) {
        int row = m0 + wr * WM + mi * 16 + fg * 4 + i;
        int col = n0 + wc * WN + ni * 16 + fr;
        float v = acc[mi][ni][i];
        size_t idx = (size_t)row * N + col;
        if constexpr (MODE == 0) {
          obf[idx] = f2bf(v);
        } else if constexpr (MODE == 1) {
          float t = e1[idx] + 0.2f * v + e2[col];
          of32[idx] = t;
          obf[idx] = f2bf(t);
        } else if constexpr (MODE == 2) {
          float t = v + e1[col];
          t = t > 0.f ? t : 0.f;
          obf[idx] = f2bf(t);
        } else {
          part[idx] = v;
        }
      }
    }
  }
}

// ---------------- ffn2 split-K reduce + residual + biases ----------------
// out = p0+p1+p2+p3 + x1f + b2[col] + nb2[col]
__global__ void k_ffn2_reduce(const float* __restrict__ p, const float* __restrict__ x1f,
                              const float* __restrict__ b2, const float* __restrict__ nb2,
                              float* __restrict__ out) {
  int i = blockIdx.x * 256 + threadIdx.x;         // float4 index
  int col4 = (i * 4) % HDIM;
  float4 s = reinterpret_cast<const float4*>(x1f)[i];
  float4 bb = *reinterpret_cast<const float4*>(b2 + col4);
  float4 nn = *reinterpret_cast<const float4*>(nb2 + col4);
  s.x += bb.x + nn.x; s.y += bb.y + nn.y; s.z += bb.z + nn.z; s.w += bb.w + nn.w;
#pragma unroll
  for (int z = 0; z < 4; z++) {
    float4 pv = reinterpret_cast<const float4*>(p + (size_t)z * ROWS * HDIM)[i];
    s.x += pv.x; s.y += pv.y; s.z += pv.z; s.w += pv.w;
  }
  reinterpret_cast<float4*>(out)[i] = s;
}

// ---------------- fused 2quad attention ----------------
__global__ __launch_bounds__(256) void k_attn(
    const u16* __restrict__ qkv, const float* __restrict__ mask,
    const float* __restrict__ tau, u16* __restrict__ outp) {
  __shared__ u16 Ks[64 * 72];
  __shared__ u16 Vt[64 * 72];
  __shared__ u16 Ps[4][16 * 72];
  int tid = threadIdx.x, lane = tid & 63, w = tid >> 6;
  int h = blockIdx.y, b = blockIdx.z;
  int fr = lane & 15, fg = lane >> 4, fk = fg * 8;
  int rb = b * SEQ;
  float rs = 1.0f / (8.0f * tau[h]);

  int t0 = blockIdx.x * 64 + w * 16;
  const u16* qrow = qkv + (size_t)(rb + t0 + fr) * QKV3 + h * 64;
  bf16x8 aq0 = *reinterpret_cast<const bf16x8*>(qrow + fk);
  bf16x8 aq1 = *reinterpret_cast<const bf16x8*>(qrow + 32 + fk);

  f32x4 acco[4] = {};
  float den[4] = {0.f, 0.f, 0.f, 0.f};

  int sr = tid >> 2, sq = (tid & 3) * 16;
  const u16* kg = qkv + (size_t)(rb + sr) * QKV3 + HDIM + h * 64 + sq;
  const u16* vg = qkv + (size_t)(rb + sr) * QKV3 + 2 * HDIM + h * 64 + sq;

  for (int st = 0; st < SEQ; st += 64) {
    int4 kv0 = *reinterpret_cast<const int4*>(kg + (size_t)st * QKV3);
    int4 kv1 = *reinterpret_cast<const int4*>(kg + (size_t)st * QKV3 + 8);
    int4 vv0 = *reinterpret_cast<const int4*>(vg + (size_t)st * QKV3);
    int4 vv1 = *reinterpret_cast<const int4*>(vg + (size_t)st * QKV3 + 8);
    __syncthreads();
    *reinterpret_cast<int4*>(&Ks[sr * 72 + sq]) = kv0;
    *reinterpret_cast<int4*>(&Ks[sr * 72 + sq + 8]) = kv1;
    const u16* vp0 = reinterpret_cast<const u16*>(&vv0);
    const u16* vp1 = reinterpret_cast<const u16*>(&vv1);
#pragma unroll
    for (int i = 0; i < 8; i++) Vt[(sq + i) * 72 + sr] = vp0[i];
#pragma unroll
    for (int i = 0; i < 8; i++) Vt[(sq + 8 + i) * 72 + sr] = vp1[i];
    __syncthreads();

#pragma unroll
    for (int sf = 0; sf < 4; sf++) {
      bf16x8 bk0 = *reinterpret_cast<const bf16x8*>(&Ks[(sf * 16 + fr) * 72 + fk]);
      bf16x8 bk1 = *reinterpret_cast<const bf16x8*>(&Ks[(sf * 16 + fr) * 72 + 32 + fk]);
      f32x4 s = {};
      s = __builtin_amdgcn_mfma_f32_16x16x32_bf16(aq0, bk0, s, 0, 0, 0);
      s = __builtin_amdgcn_mfma_f32_16x16x32_bf16(aq1, bk1, s, 0, 0, 0);
      float mval = mask[b * SEQ + st + sf * 16 + fr];
#pragma unroll
      for (int i = 0; i < 4; i++) {
        float sv = s[i] * rs;
        float wv = sv * sv * mval;
        Ps[w][(fg * 4 + i) * 72 + sf * 16 + fr] = f2bf(wv);
        wv += __shfl_xor(wv, 1);
        wv += __shfl_xor(wv, 2);
        wv += __shfl_xor(wv, 4);
        wv += __shfl_xor(wv, 8);
        den[i] += wv;
      }
    }
    bf16x8 ap0 = *reinterpret_cast<const bf16x8*>(&Ps[w][fr * 72 + fk]);
    bf16x8 ap1 = *reinterpret_cast<const bf16x8*>(&Ps[w][fr * 72 + 32 + fk]);
#pragma unroll
    for (int df = 0; df < 4; df++) {
      bf16x8 bv0 = *reinterpret_cast<const bf16x8*>(&Vt[(df * 16 + fr) * 72 + fk]);
      bf16x8 bv1 = *reinterpret_cast<const bf16x8*>(&Vt[(df * 16 + fr) * 72 + 32 + fk]);
      acco[df] = __builtin_amdgcn_mfma_f32_16x16x32_bf16(ap0, bv0, acco[df], 0, 0, 0);
      acco[df] = __builtin_amdgcn_mfma_f32_16x16x32_bf16(ap1, bv1, acco[df], 0, 0, 0);
    }
  }

#pragma unroll
  for (int df = 0; df < 4; df++)
#pragma unroll
    for (int i = 0; i < 4; i++) {
      int t = t0 + fg * 4 + i;
      int col = h * 64 + df * 16 + fr;
      float o = acco[df][i] / (den[i] + 1e-6f);
      outp[(size_t)(rb + t) * HDIM + col] = f2bf(o);
    }
}

extern "C" void kernel_launch(void* const* d_in, const int* in_sizes, int n_in,
                              void* d_out, int out_size, void* d_ws, size_t ws_size,
                              hipStream_t stream) {
  const float* x     = (const float*)d_in[0];
  const float* mask  = (const float*)d_in[1];
  const float* w_qkv = (const float*)d_in[2];
  const float* w_o   = (const float*)d_in[3];
  const float* tau   = (const float*)d_in[4];
  const float* w1    = (const float*)d_in[5];
  const float* b1    = (const float*)d_in[6];
  const float* w2    = (const float*)d_in[7];
  const float* b2    = (const float*)d_in[8];
  const float* nb1   = (const float*)d_in[9];
  const float* nb2   = (const float*)d_in[10];
  float* out = (float*)d_out;
  (void)ws_size; (void)in_sizes; (void)n_in; (void)out_size;

  // workspace layout with lifetime overlay:
  // [0 .. 50.33MB) : ffn2 partials [4][ROWS][HDIM] f32  (live only during ffn2)
  //   overlaid early-phase buffers (all dead before ffn2):
  //   xb@0, wqkvT@6.29M, woT@9.83M, w1T@11.01M, qkvb@15.73M, attnb@34.60M, x1b@40.89M
  char* base = (char*)d_ws;
  float* part = (float*)base;
  u16* xb    = (u16*)(base);
  u16* wqkvT = (u16*)(base + 6291456);
  u16* woT   = (u16*)(base + 9830400);
  u16* w1T   = (u16*)(base + 11010048);
  u16* qkvb  = (u16*)(base + 15728640);
  u16* attnb = (u16*)(base + 34603008);
  u16* x1b   = (u16*)(base + 40894464);
  u16* w2T   = (u16*)(base + 50331648);
  float* x1f = (float*)(base + 55050240);
  u16* hb    = (u16*)(base + 67633152);
  // total ws use: 92,798,976 bytes

  // pre-pass: conversions + weight transposes
  k_f32_to_bf16<<<(ROWS * HDIM / 4 + 255) / 256, 256, 0, stream>>>(x, xb, ROWS * HDIM / 4);
  k_transpose_bf16<<<dim3(QKV3 / 32, HDIM / 32), 256, 0, stream>>>(w_qkv, wqkvT, HDIM, QKV3);
  k_transpose_bf16<<<dim3(HDIM / 32, HDIM / 32), 256, 0, stream>>>(w_o, woT, HDIM, HDIM);
  k_transpose_bf16<<<dim3(INTERDIM / 32, HDIM / 32), 256, 0, stream>>>(w1, w1T, HDIM, INTERDIM);
  k_transpose_bf16<<<dim3(HDIM / 32, INTERDIM / 32), 256, 0, stream>>>(w2, w2T, INTERDIM, HDIM);

  // qkv = x @ w_qkv  -> bf16
  k_gemm<128, 0><<<dim3(QKV3 / 128, ROWS / 128), 256, 0, stream>>>(
      xb, wqkvT, ROWS, QKV3, HDIM, 1, qkvb, nullptr, nullptr, nullptr);
  // attention
  k_attn<<<dim3(SEQ / 64, NHEADS, NBATCH), 256, 0, stream>>>(qkvb, mask, tau, attnb);
  // x1 = x + 0.2*(attn @ w_o) + nb1   (BN=64 -> 12x32 grid)
  k_gemm<64, 1><<<dim3(HDIM / 64, ROWS / 128), 256, 0, stream>>>(
      attnb, woT, ROWS, HDIM, HDIM, 1, x1b, x1f, x, nb1);
  // h = relu(x1 @ w1 + b1)
  k_gemm<128, 2><<<dim3(INTERDIM / 128, ROWS / 128), 256, 0, stream>>>(
      x1b, w1T, ROWS, INTERDIM, HDIM, 1, hb, nullptr, b1, nullptr);
  // ffn2 split-K=4 partials
  k_gemm<128, 3><<<dim3(HDIM / 128, ROWS / 128, 4), 256, 0, stream>>>(
      hb, w2T, ROWS, HDIM, INTERDIM, 4, nullptr, part, nullptr, nullptr);
  // out = sum(partials) + x1f + b2 + nb2
  k_ffn2_reduce<<<ROWS * HDIM / 4 / 256, 256, 0, stream>>>(part, x1f, b2, nb2, out);
}

// Round 3
// 193.188 us; speedup vs baseline: 1.5650x; 1.1565x over previous
//
#include <hip/hip_runtime.h>

typedef __bf16 bf16x8 __attribute__((ext_vector_type(8)));
typedef float f32x4 __attribute__((ext_vector_type(4)));
typedef unsigned short u16;
typedef unsigned long long u64;

#define HDIM 768
#define NHEADS 12
#define SEQ 1024
#define NBATCH 4
#define ROWS 4096      // B*T
#define QKV3 2304
#define INTERDIM 3072

__device__ __forceinline__ u16 f2bf(float f) {
  union { float f; unsigned int u; } v; v.f = f;
  unsigned int r = v.u + 0x7fffu + ((v.u >> 16) & 1u);
  return (u16)(r >> 16);
}

// async global->LDS, 16B per lane. LDS dest is wave-uniform base + lane*16.
__device__ __forceinline__ void gload16(const u16* g, u16* l) {
  __builtin_amdgcn_global_load_lds(
      (const __attribute__((address_space(1))) void*)g,
      (__attribute__((address_space(3))) void*)l, 16, 0, 0);
}

__device__ __forceinline__ unsigned ldsoff(const void* p) {
  return (unsigned)(unsigned long long)(const __attribute__((address_space(3))) char*)p;
}

// hardware transpose read: lane gets 4 bf16 at [a, a+32B, a+64B, a+96B]
__device__ __forceinline__ u64 tr8(unsigned a) {
  u64 r;
  asm volatile("ds_read_b64_tr_b16 %0, %1" : "=v"(r) : "v"(a));
  return r;
}

union B8 { u64 q[2]; bf16x8 v; };

// ---------------- f32 -> bf16 copy (vectorized x4) ----------------
__global__ void k_f32_to_bf16(const float* __restrict__ in, u16* __restrict__ out, int n4) {
  int i = blockIdx.x * 256 + threadIdx.x;
  if (i < n4) {
    float4 f = reinterpret_cast<const float4*>(in)[i];
    ushort4 o;
    o.x = f2bf(f.x); o.y = f2bf(f.y); o.z = f2bf(f.z); o.w = f2bf(f.w);
    reinterpret_cast<ushort4*>(out)[i] = o;
  }
}

// ---------------- f32 [K][N] -> bf16 [N][K] transpose ----------------
__global__ void k_transpose_bf16(const float* __restrict__ in, u16* __restrict__ out,
                                 int K, int N) {
  __shared__ float tile[32][33];
  int tx = threadIdx.x & 31, ty = threadIdx.x >> 5;
  int n0 = blockIdx.x * 32, k0 = blockIdx.y * 32;
#pragma unroll
  for (int i = 0; i < 32; i += 8)
    tile[ty + i][tx] = in[(size_t)(k0 + ty + i) * N + n0 + tx];
  __syncthreads();
#pragma unroll
  for (int i = 0; i < 32; i += 8)
    out[(size_t)(n0 + ty + i) * K + k0 + tx] = f2bf(tile[tx][ty + i]);
}

// ---------------- bf16 MFMA GEMM: C = A[M][K] * Bt[N][K]^T ----------------
template<int BN, int MODE>
__global__ __launch_bounds__(256) void k_gemm(
    const u16* __restrict__ A, const u16* __restrict__ Bt,
    int M, int N, int K, int ksplit,
    u16* __restrict__ obf, float* __restrict__ of32,
    const float* __restrict__ e1, const float* __restrict__ e2) {
  constexpr int BM = 128, BK = 32;
  constexpr int WC = (BN == 128) ? 2 : 1;
  constexpr int WR = 4 / WC;
  constexpr int WM = BM / WR;
  constexpr int WN = BN / WC;
  constexpr int MFR = WM / 16;
  constexpr int NFR = WN / 16;
  __shared__ u16 As[BM * BK];
  __shared__ u16 Bs[BN * BK];
  int tid = threadIdx.x, lane = tid & 63, wid = tid >> 6;
  int wr = wid / WC, wc = wid % WC;
  int m0 = blockIdx.y * BM, n0 = blockIdx.x * BN;
  int Kc = K / ksplit, k0 = blockIdx.z * Kc;
  int fr = lane & 15, fg = lane >> 4, fk = fg * 8;

  f32x4 acc[MFR][NFR] = {};

  int e = tid * 8;
  int r = e >> 5, c = e & 31;
  const u16* Ag = A + (size_t)(m0 + r) * K + k0 + c;
  const u16* Bg = Bt + (size_t)(n0 + r) * K + k0 + c;
  u16* Asl = &As[wid * 512];
  u16* Bsl = &Bs[wid * 512];

  for (int kt = 0; kt < Kc; kt += BK) {
    __syncthreads();
    gload16(Ag + kt, Asl);
    gload16(Ag + kt + (size_t)64 * K, Asl + 2048);
    gload16(Bg + kt, Bsl);
    if (BN == 128) gload16(Bg + kt + (size_t)64 * K, Bsl + 2048);
    __syncthreads();

    bf16x8 af[MFR], bfv[NFR];
#pragma unroll
    for (int mi = 0; mi < MFR; mi++)
      af[mi] = *reinterpret_cast<const bf16x8*>(&As[(wr * WM + mi * 16 + fr) * BK + fk]);
#pragma unroll
    for (int ni = 0; ni < NFR; ni++)
      bfv[ni] = *reinterpret_cast<const bf16x8*>(&Bs[(wc * WN + ni * 16 + fr) * BK + fk]);
#pragma unroll
    for (int mi = 0; mi < MFR; mi++)
#pragma unroll
      for (int ni = 0; ni < NFR; ni++)
        acc[mi][ni] = __builtin_amdgcn_mfma_f32_16x16x32_bf16(af[mi], bfv[ni], acc[mi][ni], 0, 0, 0);
  }

  float* part = (MODE == 3) ? of32 + (size_t)blockIdx.z * ((size_t)M * N) : of32;
#pragma unroll
  for (int mi = 0; mi < MFR; mi++) {
#pragma unroll
    for (int ni = 0; ni < NFR; ni++) {
#pragma unroll
      for (int i = 0; i < 4; i++) {
        int row = m0 + wr * WM + mi * 16 + fg * 4 + i;
        int col = n0 + wc * WN + ni * 16 + fr;
        float v = acc[mi][ni][i];
        size_t idx = (size_t)row * N + col;
        if constexpr (MODE == 0) {
          obf[idx] = f2bf(v);
        } else if constexpr (MODE == 1) {
          float t = e1[idx] + 0.2f * v + e2[col];
          of32[idx] = t;
          obf[idx] = f2bf(t);
        } else if constexpr (MODE == 2) {
          float t = v + e1[col];
          t = t > 0.f ? t : 0.f;
          obf[idx] = f2bf(t);
        } else {
          part[idx] = v;
        }
      }
    }
  }
}

// ---------------- ffn2 split-K reduce + residual + biases ----------------
__global__ void k_ffn2_reduce(const float* __restrict__ p, const float* __restrict__ x1f,
                              const float* __restrict__ b2, const float* __restrict__ nb2,
                              float* __restrict__ out) {
  int i = blockIdx.x * 256 + threadIdx.x;
  int col4 = (i * 4) % HDIM;
  float4 s = reinterpret_cast<const float4*>(x1f)[i];
  float4 bb = *reinterpret_cast<const float4*>(b2 + col4);
  float4 nn = *reinterpret_cast<const float4*>(nb2 + col4);
  s.x += bb.x + nn.x; s.y += bb.y + nn.y; s.z += bb.z + nn.z; s.w += bb.w + nn.w;
#pragma unroll
  for (int z = 0; z < 4; z++) {
    float4 pv = reinterpret_cast<const float4*>(p + (size_t)z * ROWS * HDIM)[i];
    s.x += pv.x; s.y += pv.y; s.z += pv.z; s.w += pv.w;
  }
  reinterpret_cast<float4*>(out)[i] = s;
}

// ---------------- fused 2quad attention (8 waves, 128 q-rows/block) ----------------
// Per tile: K staged padded row-major (b128 r/w); V staged 4x16-subtiled, read
// via ds_read_b64_tr_b16; P^T packed per-wave, read via tr_read; den via
// MFMA with all-ones B operand.
__global__ __launch_bounds__(512) void k_attn(
    const u16* __restrict__ qkv, const float* __restrict__ mask,
    const float* __restrict__ tau, u16* __restrict__ outp) {
  __shared__ u16 Ks[64 * 72];     // [s][d] padded
  __shared__ u16 Vs[64 * 64];     // subtiled: block(sg,dj)=sg*4+dj, 4s x 16d each
  __shared__ u16 Ps[8 * 1024];    // per-wave P^T subtiled: 16 blocks of 4s x 16t
  int tid = threadIdx.x, lane = tid & 63, w = tid >> 6;
  int h = blockIdx.y, b = blockIdx.z;
  int fr = lane & 15, fg = lane >> 4, fk = fg * 8;
  int rb = b * SEQ;
  float rs = 1.0f / (8.0f * tau[h]);
  float rs2 = rs * rs;

  int t0 = blockIdx.x * 128 + w * 16;
  const u16* qrow = qkv + (size_t)(rb + t0 + fr) * QKV3 + h * 64;
  bf16x8 aq0 = *reinterpret_cast<const bf16x8*>(qrow + fk);
  bf16x8 aq1 = *reinterpret_cast<const bf16x8*>(qrow + 32 + fk);

  f32x4 acco[4] = {};
  f32x4 accd = {};

  // staging: thread -> (row sr, 8-elem chunk c)
  int sr = tid >> 3, c = tid & 7;
  const u16* kg = qkv + (size_t)(rb + sr) * QKV3 + HDIM + h * 64 + c * 8;
  const u16* vg = kg + HDIM;
  u16* kw = &Ks[sr * 72 + c * 8];
  u16* vw = &Vs[((sr >> 2) * 4 + (c >> 1)) * 64 + (sr & 3) * 16 + (c & 1) * 8];
  unsigned psb = ldsoff(&Ps[w * 1024]);
  unsigned vsb = ldsoff(Vs);

  __bf16 onev = (__bf16)1.0f;
  bf16x8 ones = {onev, onev, onev, onev, onev, onev, onev, onev};

  int4 kreg = *reinterpret_cast<const int4*>(kg);
  int4 vreg = *reinterpret_cast<const int4*>(vg);

  for (int st = 0; st < SEQ; st += 64) {
    __syncthreads();
    *reinterpret_cast<int4*>(kw) = kreg;
    *reinterpret_cast<int4*>(vw) = vreg;
    __syncthreads();
    if (st + 64 < SEQ) {  // T14: prefetch next tile under compute
      kreg = *reinterpret_cast<const int4*>(kg + (size_t)(st + 64) * QKV3);
      vreg = *reinterpret_cast<const int4*>(vg + (size_t)(st + 64) * QKV3);
    }

    // ---- QK^T + P^T pack ----
#pragma unroll
    for (int sf = 0; sf < 4; sf++) {
      bf16x8 bk0 = *reinterpret_cast<const bf16x8*>(&Ks[(sf * 16 + fr) * 72 + fk]);
      bf16x8 bk1 = *reinterpret_cast<const bf16x8*>(&Ks[(sf * 16 + fr) * 72 + 32 + fk]);
      f32x4 s = {};
      s = __builtin_amdgcn_mfma_f32_16x16x32_bf16(aq0, bk0, s, 0, 0, 0);
      s = __builtin_amdgcn_mfma_f32_16x16x32_bf16(aq1, bk1, s, 0, 0, 0);
      float rm = rs2 * mask[b * SEQ + st + sf * 16 + fr];
      u64 pw = 0;
#pragma unroll
      for (int i = 0; i < 4; i++) {
        float wv = s[i] * s[i] * rm;
        pw |= (u64)f2bf(wv) << (16 * i);
      }
      // P^T[s=sf*16+fr][t=fg*4..+3]: block sf*4+(fr>>2), row fr&3, col fg*4
      *reinterpret_cast<u64*>(&Ps[w * 1024 + (sf * 4 + (fr >> 2)) * 64 + (fr & 3) * 16 + fg * 4]) = pw;
    }
    asm volatile("s_waitcnt lgkmcnt(0)" ::: "memory");
    __builtin_amdgcn_sched_barrier(0);

    // ---- PV via tr reads ----
    u64 pa0 = tr8(psb + (fg * 2 + 0) * 128 + fr * 2);
    u64 pa1 = tr8(psb + (fg * 2 + 1) * 128 + fr * 2);
    u64 pa2 = tr8(psb + (8 + fg * 2 + 0) * 128 + fr * 2);
    u64 pa3 = tr8(psb + (8 + fg * 2 + 1) * 128 + fr * 2);
    u64 vb[4][4];
#pragma unroll
    for (int df = 0; df < 4; df++) {
      vb[df][0] = tr8(vsb + ((fg * 2 + 0) * 4 + df) * 128 + fr * 2);
      vb[df][1] = tr8(vsb + ((fg * 2 + 1) * 4 + df) * 128 + fr * 2);
      vb[df][2] = tr8(vsb + ((8 + fg * 2 + 0) * 4 + df) * 128 + fr * 2);
      vb[df][3] = tr8(vsb + ((8 + fg * 2 + 1) * 4 + df) * 128 + fr * 2);
    }
    asm volatile("s_waitcnt lgkmcnt(0)" ::: "memory");
    __builtin_amdgcn_sched_barrier(0);

    B8 ap0, ap1;
    ap0.q[0] = pa0; ap0.q[1] = pa1;
    ap1.q[0] = pa2; ap1.q[1] = pa3;
#pragma unroll
    for (int df = 0; df < 4; df++) {
      B8 b0, b1;
      b0.q[0] = vb[df][0]; b0.q[1] = vb[df][1];
      b1.q[0] = vb[df][2]; b1.q[1] = vb[df][3];
      acco[df] = __builtin_amdgcn_mfma_f32_16x16x32_bf16(ap0.v, b0.v, acco[df], 0, 0, 0);
      acco[df] = __builtin_amdgcn_mfma_f32_16x16x32_bf16(ap1.v, b1.v, acco[df], 0, 0, 0);
    }
    accd = __builtin_amdgcn_mfma_f32_16x16x32_bf16(ap0.v, ones, accd, 0, 0, 0);
    accd = __builtin_amdgcn_mfma_f32_16x16x32_bf16(ap1.v, ones, accd, 0, 0, 0);
  }

#pragma unroll
  for (int df = 0; df < 4; df++)
#pragma unroll
    for (int i = 0; i < 4; i++) {
      int t = t0 + fg * 4 + i;
      int col = h * 64 + df * 16 + fr;
      float o = acco[df][i] / (accd[i] + 1e-6f);
      outp[(size_t)(rb + t) * HDIM + col] = f2bf(o);
    }
}

extern "C" void kernel_launch(void* const* d_in, const int* in_sizes, int n_in,
                              void* d_out, int out_size, void* d_ws, size_t ws_size,
                              hipStream_t stream) {
  const float* x     = (const float*)d_in[0];
  const float* mask  = (const float*)d_in[1];
  const float* w_qkv = (const float*)d_in[2];
  const float* w_o   = (const float*)d_in[3];
  const float* tau   = (const float*)d_in[4];
  const float* w1    = (const float*)d_in[5];
  const float* b1    = (const float*)d_in[6];
  const float* w2    = (const float*)d_in[7];
  const float* b2    = (const float*)d_in[8];
  const float* nb1   = (const float*)d_in[9];
  const float* nb2   = (const float*)d_in[10];
  float* out = (float*)d_out;
  (void)ws_size; (void)in_sizes; (void)n_in; (void)out_size;

  char* base = (char*)d_ws;
  float* part = (float*)base;
  u16* xb    = (u16*)(base);
  u16* wqkvT = (u16*)(base + 6291456);
  u16* woT   = (u16*)(base + 9830400);
  u16* w1T   = (u16*)(base + 11010048);
  u16* qkvb  = (u16*)(base + 15728640);
  u16* attnb = (u16*)(base + 34603008);
  u16* x1b   = (u16*)(base + 40894464);
  u16* w2T   = (u16*)(base + 50331648);
  float* x1f = (float*)(base + 55050240);
  u16* hb    = (u16*)(base + 67633152);

  k_f32_to_bf16<<<(ROWS * HDIM / 4 + 255) / 256, 256, 0, stream>>>(x, xb, ROWS * HDIM / 4);
  k_transpose_bf16<<<dim3(QKV3 / 32, HDIM / 32), 256, 0, stream>>>(w_qkv, wqkvT, HDIM, QKV3);
  k_transpose_bf16<<<dim3(HDIM / 32, HDIM / 32), 256, 0, stream>>>(w_o, woT, HDIM, HDIM);
  k_transpose_bf16<<<dim3(INTERDIM / 32, HDIM / 32), 256, 0, stream>>>(w1, w1T, HDIM, INTERDIM);
  k_transpose_bf16<<<dim3(HDIM / 32, INTERDIM / 32), 256, 0, stream>>>(w2, w2T, INTERDIM, HDIM);

  k_gemm<128, 0><<<dim3(QKV3 / 128, ROWS / 128), 256, 0, stream>>>(
      xb, wqkvT, ROWS, QKV3, HDIM, 1, qkvb, nullptr, nullptr, nullptr);
  k_attn<<<dim3(SEQ / 128, NHEADS, NBATCH), 512, 0, stream>>>(qkvb, mask, tau, attnb);
  k_gemm<64, 1><<<dim3(HDIM / 64, ROWS / 128), 256, 0, stream>>>(
      attnb, woT, ROWS, HDIM, HDIM, 1, x1b, x1f, x, nb1);
  k_gemm<128, 2><<<dim3(INTERDIM / 128, ROWS / 128), 256, 0, stream>>>(
      x1b, w1T, ROWS, INTERDIM, HDIM, 1, hb, nullptr, b1, nullptr);
  k_gemm<128, 3><<<dim3(HDIM / 128, ROWS / 128, 4), 256, 0, stream>>>(
      hb, w2T, ROWS, HDIM, INTERDIM, 4, nullptr, part, nullptr, nullptr);
  k_ffn2_reduce<<<ROWS * HDIM / 4 / 256, 256, 0, stream>>>(part, x1f, b2, nb2, out);
}

// Round 4
// 164.565 us; speedup vs baseline: 1.8373x; 1.1739x over previous
//
#include <hip/hip_runtime.h>

typedef __bf16 bf16x8 __attribute__((ext_vector_type(8)));
typedef float f32x4 __attribute__((ext_vector_type(4)));
typedef unsigned short u16;
typedef unsigned long long u64;

#define HDIM 768
#define NHEADS 12
#define SEQ 1024
#define NBATCH 4
#define ROWS 4096      // B*T
#define QKV3 2304
#define INTERDIM 3072

__device__ __forceinline__ u16 f2bf(float f) {
  union { float f; unsigned int u; } v; v.f = f;
  unsigned int r = v.u + 0x7fffu + ((v.u >> 16) & 1u);
  return (u16)(r >> 16);
}

// async global->LDS, 16B per lane. LDS dest is wave-uniform base + lane*16.
__device__ __forceinline__ void gload16(const u16* g, u16* l) {
  __builtin_amdgcn_global_load_lds(
      (const __attribute__((address_space(1))) void*)g,
      (__attribute__((address_space(3))) void*)l, 16, 0, 0);
}

__device__ __forceinline__ unsigned ldsoff(const void* p) {
  return (unsigned)(unsigned long long)(const __attribute__((address_space(3))) char*)p;
}

// hardware transpose read: lane gets 4 bf16 at [a, a+32B, a+64B, a+96B]
__device__ __forceinline__ u64 tr8(unsigned a) {
  u64 r;
  asm volatile("ds_read_b64_tr_b16 %0, %1" : "=v"(r) : "v"(a));
  return r;
}

union B8 { u64 q[2]; bf16x8 v; };

// ---------------- fused pre-pass: x->bf16 + 4 weight transposes ----------------
// blocks [0,3072): x f32->bf16 (float4 per thread)
// then 32x32 transpose tiles: wqkv 1728, wo 576, w1 2304, w2 2304  (total 9984)
__global__ __launch_bounds__(256) void k_prep(
    const float* __restrict__ x, u16* __restrict__ xb,
    const float* __restrict__ wqkv, u16* __restrict__ wqkvT,
    const float* __restrict__ wo, u16* __restrict__ woT,
    const float* __restrict__ w1, u16* __restrict__ w1T,
    const float* __restrict__ w2, u16* __restrict__ w2T) {
  __shared__ float tile[32][33];
  int bid = blockIdx.x, tid = threadIdx.x;
  if (bid < 3072) {
    int i = bid * 256 + tid;
    float4 f = reinterpret_cast<const float4*>(x)[i];
    ushort4 o;
    o.x = f2bf(f.x); o.y = f2bf(f.y); o.z = f2bf(f.z); o.w = f2bf(f.w);
    reinterpret_cast<ushort4*>(xb)[i] = o;
    return;
  }
  const float* in; u16* outp; int K, N, t;
  if (bid < 4800)      { in = wqkv; outp = wqkvT; K = 768;  N = 2304; t = bid - 3072; }
  else if (bid < 5376) { in = wo;   outp = woT;   K = 768;  N = 768;  t = bid - 4800; }
  else if (bid < 7680) { in = w1;   outp = w1T;   K = 768;  N = 3072; t = bid - 5376; }
  else                 { in = w2;   outp = w2T;   K = 3072; N = 768;  t = bid - 7680; }
  int ntx = N >> 5;
  int bx = t % ntx, by = t / ntx;
  int tx = tid & 31, ty = tid >> 5;
  int n0 = bx * 32, k0 = by * 32;
#pragma unroll
  for (int i = 0; i < 32; i += 8)
    tile[ty + i][tx] = in[(size_t)(k0 + ty + i) * N + n0 + tx];
  __syncthreads();
#pragma unroll
  for (int i = 0; i < 32; i += 8)
    outp[(size_t)(n0 + ty + i) * K + k0 + tx] = f2bf(tile[tx][ty + i]);
}

// ---------------- bf16 MFMA GEMM: C = A[M][K] * Bt[N][K]^T ----------------
// BM=128, BK=64, linear LDS dest via global_load_lds; bank-conflict fix via
// pre-swizzled GLOBAL source + matching XOR on ds_read (rule #21: both sides).
// swizzle: elem col ^= (row&3)<<4  (byte bits 5-6 ^= row bits 0-1; involution)
// BN=128: 4 waves 2x2, wave tile 64x64. BN=64: 4 waves 4x1, wave tile 32x64.
// modes: 0: obf=bf16(C)                                   (qkv)
//        1: t=e1[idx]+0.2*C+e2[col]; of32=t, obf=bf16(t)  (w_o + residual)
//        2: t=relu(C+e1[col]); obf=bf16(t)                (ffn1)
//        3: of32[z*M*N+idx] = C                           (ffn2 split-K partial)
template<int BN, int MODE>
__global__ __launch_bounds__(256) void k_gemm(
    const u16* __restrict__ A, const u16* __restrict__ Bt,
    int M, int N, int K, int ksplit,
    u16* __restrict__ obf, float* __restrict__ of32,
    const float* __restrict__ e1, const float* __restrict__ e2) {
  constexpr int BM = 128, BK = 64;
  constexpr int WC = (BN == 128) ? 2 : 1;
  constexpr int WR = 4 / WC;
  constexpr int WM = BM / WR;
  constexpr int WN = BN / WC;
  constexpr int MFR = WM / 16;
  constexpr int NFR = WN / 16;
  constexpr int AISS = BM / 32;   // global_load_lds issues for A per K-step
  constexpr int BISS = BN / 32;
  __shared__ u16 As[BM * BK];
  __shared__ u16 Bs[BN * BK];
  int tid = threadIdx.x, lane = tid & 63, wid = tid >> 6;
  int wr = wid / WC, wc = wid % WC;

  // T1: bijective XCD swizzle on flattened x-y (all grids have nwg%8==0)
  int gx = gridDim.x;
  int nwg = gx * gridDim.y;
  int orig = blockIdx.y * gx + blockIdx.x;
  int cpx = nwg >> 3;
  int swz = (orig & 7) * cpx + (orig >> 3);
  int bx = swz % gx, by = swz / gx;

  int m0 = by * BM, n0 = bx * BN;
  int Kc = K / ksplit, k0 = blockIdx.z * Kc;
  int fr = lane & 15, fg = lane >> 4, fk = fg * 8;

  f32x4 acc[MFR][NFR] = {};

  // staging: thread -> (row r within 32-row issue group, swizzled 8-elem col)
  int r = tid >> 3;                                   // 0..31
  int cswz = ((tid & 7) * 8) ^ ((r & 3) << 4);        // pre-swizzled source col
  const u16* Ag = A + (size_t)(m0 + r) * K + k0 + cswz;
  const u16* Bg = Bt + (size_t)(n0 + r) * K + k0 + cswz;
  u16* Asl = &As[wid * 512];   // wave-uniform LDS base (lane adds *16B in HW)
  u16* Bsl = &Bs[wid * 512];

  for (int kt = 0; kt < Kc; kt += BK) {
    __syncthreads();
#pragma unroll
    for (int i = 0; i < AISS; i++)
      gload16(Ag + kt + (size_t)(i * 32) * K, Asl + i * 2048);
#pragma unroll
    for (int i = 0; i < BISS; i++)
      gload16(Bg + kt + (size_t)(i * 32) * K, Bsl + i * 2048);
    __syncthreads();  // compiler drains vmcnt(0) -> LDS tile ready

#pragma unroll
    for (int kk = 0; kk < 2; kk++) {
      bf16x8 af[MFR], bfv[NFR];
#pragma unroll
      for (int mi = 0; mi < MFR; mi++) {
        int row = wr * WM + mi * 16 + fr;
        int ce = (kk * 32 + fk) ^ ((row & 3) << 4);
        af[mi] = *reinterpret_cast<const bf16x8*>(&As[row * BK + ce]);
      }
#pragma unroll
      for (int ni = 0; ni < NFR; ni++) {
        int row = wc * WN + ni * 16 + fr;
        int ce = (kk * 32 + fk) ^ ((row & 3) << 4);
        bfv[ni] = *reinterpret_cast<const bf16x8*>(&Bs[row * BK + ce]);
      }
#pragma unroll
      for (int mi = 0; mi < MFR; mi++)
#pragma unroll
        for (int ni = 0; ni < NFR; ni++)
          acc[mi][ni] = __builtin_amdgcn_mfma_f32_16x16x32_bf16(af[mi], bfv[ni], acc[mi][ni], 0, 0, 0);
    }
  }

  float* part = (MODE == 3) ? of32 + (size_t)blockIdx.z * ((size_t)M * N) : of32;
#pragma unroll
  for (int mi = 0; mi < MFR; mi++) {
#pragma unroll
    for (int ni = 0; ni < NFR; ni++) {
#pragma unroll
      for (int i = 0; i < 4; i++) {
        int row = m0 + wr * WM + mi * 16 + fg * 4 + i;
        int col = n0 + wc * WN + ni * 16 + fr;
        float v = acc[mi][ni][i];
        size_t idx = (size_t)row * N + col;
        if constexpr (MODE == 0) {
          obf[idx] = f2bf(v);
        } else if constexpr (MODE == 1) {
          float t = e1[idx] + 0.2f * v + e2[col];
          of32[idx] = t;
          obf[idx] = f2bf(t);
        } else if constexpr (MODE == 2) {
          float t = v + e1[col];
          t = t > 0.f ? t : 0.f;
          obf[idx] = f2bf(t);
        } else {
          part[idx] = v;
        }
      }
    }
  }
}

// ---------------- ffn2 split-K reduce + residual + biases ----------------
// out = p0+p1 + x1f + b2[col] + nb2[col]
__global__ void k_ffn2_reduce(const float* __restrict__ p, const float* __restrict__ x1f,
                              const float* __restrict__ b2, const float* __restrict__ nb2,
                              float* __restrict__ out) {
  int i = blockIdx.x * 256 + threadIdx.x;
  int col4 = (i * 4) % HDIM;
  float4 s = reinterpret_cast<const float4*>(x1f)[i];
  float4 bb = *reinterpret_cast<const float4*>(b2 + col4);
  float4 nn = *reinterpret_cast<const float4*>(nb2 + col4);
  s.x += bb.x + nn.x; s.y += bb.y + nn.y; s.z += bb.z + nn.z; s.w += bb.w + nn.w;
#pragma unroll
  for (int z = 0; z < 2; z++) {
    float4 pv = reinterpret_cast<const float4*>(p + (size_t)z * ROWS * HDIM)[i];
    s.x += pv.x; s.y += pv.y; s.z += pv.z; s.w += pv.w;
  }
  reinterpret_cast<float4*>(out)[i] = s;
}

// ---------------- fused 2quad attention (8 waves, 128 q-rows/block) ----------------
__global__ __launch_bounds__(512) void k_attn(
    const u16* __restrict__ qkv, const float* __restrict__ mask,
    const float* __restrict__ tau, u16* __restrict__ outp) {
  __shared__ u16 Ks[64 * 72];     // [s][d] padded
  __shared__ u16 Vs[64 * 64];     // subtiled: block(sg,dj)=sg*4+dj, 4s x 16d each
  __shared__ u16 Ps[8 * 1024];    // per-wave P^T subtiled: 16 blocks of 4s x 16t
  int tid = threadIdx.x, lane = tid & 63, w = tid >> 6;
  int h = blockIdx.y, b = blockIdx.z;
  int fr = lane & 15, fg = lane >> 4, fk = fg * 8;
  int rb = b * SEQ;
  float rs = 1.0f / (8.0f * tau[h]);
  float rs2 = rs * rs;

  int t0 = blockIdx.x * 128 + w * 16;
  const u16* qrow = qkv + (size_t)(rb + t0 + fr) * QKV3 + h * 64;
  bf16x8 aq0 = *reinterpret_cast<const bf16x8*>(qrow + fk);
  bf16x8 aq1 = *reinterpret_cast<const bf16x8*>(qrow + 32 + fk);

  f32x4 acco[4] = {};
  f32x4 accd = {};

  int sr = tid >> 3, c = tid & 7;
  const u16* kg = qkv + (size_t)(rb + sr) * QKV3 + HDIM + h * 64 + c * 8;
  const u16* vg = kg + HDIM;
  u16* kw = &Ks[sr * 72 + c * 8];
  u16* vw = &Vs[((sr >> 2) * 4 + (c >> 1)) * 64 + (sr & 3) * 16 + (c & 1) * 8];
  unsigned psb = ldsoff(&Ps[w * 1024]);
  unsigned vsb = ldsoff(Vs);

  __bf16 onev = (__bf16)1.0f;
  bf16x8 ones = {onev, onev, onev, onev, onev, onev, onev, onev};

  int4 kreg = *reinterpret_cast<const int4*>(kg);
  int4 vreg = *reinterpret_cast<const int4*>(vg);

  for (int st = 0; st < SEQ; st += 64) {
    __syncthreads();
    *reinterpret_cast<int4*>(kw) = kreg;
    *reinterpret_cast<int4*>(vw) = vreg;
    __syncthreads();
    if (st + 64 < SEQ) {  // T14: prefetch next tile under compute
      kreg = *reinterpret_cast<const int4*>(kg + (size_t)(st + 64) * QKV3);
      vreg = *reinterpret_cast<const int4*>(vg + (size_t)(st + 64) * QKV3);
    }

    // ---- QK^T + P^T pack ----
#pragma unroll
    for (int sf = 0; sf < 4; sf++) {
      bf16x8 bk0 = *reinterpret_cast<const bf16x8*>(&Ks[(sf * 16 + fr) * 72 + fk]);
      bf16x8 bk1 = *reinterpret_cast<const bf16x8*>(&Ks[(sf * 16 + fr) * 72 + 32 + fk]);
      f32x4 s = {};
      s = __builtin_amdgcn_mfma_f32_16x16x32_bf16(aq0, bk0, s, 0, 0, 0);
      s = __builtin_amdgcn_mfma_f32_16x16x32_bf16(aq1, bk1, s, 0, 0, 0);
      float rm = rs2 * mask[b * SEQ + st + sf * 16 + fr];
      u64 pw = 0;
#pragma unroll
      for (int i = 0; i < 4; i++) {
        float wv = s[i] * s[i] * rm;
        pw |= (u64)f2bf(wv) << (16 * i);
      }
      *reinterpret_cast<u64*>(&Ps[w * 1024 + (sf * 4 + (fr >> 2)) * 64 + (fr & 3) * 16 + fg * 4]) = pw;
    }
    asm volatile("s_waitcnt lgkmcnt(0)" ::: "memory");
    __builtin_amdgcn_sched_barrier(0);

    // ---- PV via tr reads ----
    u64 pa0 = tr8(psb + (fg * 2 + 0) * 128 + fr * 2);
    u64 pa1 = tr8(psb + (fg * 2 + 1) * 128 + fr * 2);
    u64 pa2 = tr8(psb + (8 + fg * 2 + 0) * 128 + fr * 2);
    u64 pa3 = tr8(psb + (8 + fg * 2 + 1) * 128 + fr * 2);
    u64 vb[4][4];
#pragma unroll
    for (int df = 0; df < 4; df++) {
      vb[df][0] = tr8(vsb + ((fg * 2 + 0) * 4 + df) * 128 + fr * 2);
      vb[df][1] = tr8(vsb + ((fg * 2 + 1) * 4 + df) * 128 + fr * 2);
      vb[df][2] = tr8(vsb + ((8 + fg * 2 + 0) * 4 + df) * 128 + fr * 2);
      vb[df][3] = tr8(vsb + ((8 + fg * 2 + 1) * 4 + df) * 128 + fr * 2);
    }
    asm volatile("s_waitcnt lgkmcnt(0)" ::: "memory");
    __builtin_amdgcn_sched_barrier(0);

    B8 ap0, ap1;
    ap0.q[0] = pa0; ap0.q[1] = pa1;
    ap1.q[0] = pa2; ap1.q[1] = pa3;
#pragma unroll
    for (int df = 0; df < 4; df++) {
      B8 b0, b1;
      b0.q[0] = vb[df][0]; b0.q[1] = vb[df][1];
      b1.q[0] = vb[df][2]; b1.q[1] = vb[df][3];
      acco[df] = __builtin_amdgcn_mfma_f32_16x16x32_bf16(ap0.v, b0.v, acco[df], 0, 0, 0);
      acco[df] = __builtin_amdgcn_mfma_f32_16x16x32_bf16(ap1.v, b1.v, acco[df], 0, 0, 0);
    }
    accd = __builtin_amdgcn_mfma_f32_16x16x32_bf16(ap0.v, ones, accd, 0, 0, 0);
    accd = __builtin_amdgcn_mfma_f32_16x16x32_bf16(ap1.v, ones, accd, 0, 0, 0);
  }

#pragma unroll
  for (int df = 0; df < 4; df++)
#pragma unroll
    for (int i = 0; i < 4; i++) {
      int t = t0 + fg * 4 + i;
      int col = h * 64 + df * 16 + fr;
      float o = acco[df][i] / (accd[i] + 1e-6f);
      outp[(size_t)(rb + t) * HDIM + col] = f2bf(o);
    }
}

extern "C" void kernel_launch(void* const* d_in, const int* in_sizes, int n_in,
                              void* d_out, int out_size, void* d_ws, size_t ws_size,
                              hipStream_t stream) {
  const float* x     = (const float*)d_in[0];
  const float* mask  = (const float*)d_in[1];
  const float* w_qkv = (const float*)d_in[2];
  const float* w_o   = (const float*)d_in[3];
  const float* tau   = (const float*)d_in[4];
  const float* w1    = (const float*)d_in[5];
  const float* b1    = (const float*)d_in[6];
  const float* w2    = (const float*)d_in[7];
  const float* b2    = (const float*)d_in[8];
  const float* nb1   = (const float*)d_in[9];
  const float* nb2   = (const float*)d_in[10];
  float* out = (float*)d_out;
  (void)ws_size; (void)in_sizes; (void)n_in; (void)out_size;

  char* base = (char*)d_ws;
  float* part = (float*)base;                    // [2][ROWS][HDIM] f32, live only in ffn2
  u16* xb    = (u16*)(base);
  u16* wqkvT = (u16*)(base + 6291456);
  u16* woT   = (u16*)(base + 9830400);
  u16* w1T   = (u16*)(base + 11010048);
  u16* qkvb  = (u16*)(base + 15728640);
  u16* attnb = (u16*)(base + 34603008);
  u16* x1b   = (u16*)(base + 40894464);
  u16* w2T   = (u16*)(base + 50331648);
  float* x1f = (float*)(base + 55050240);
  u16* hb    = (u16*)(base + 67633152);

  k_prep<<<9984, 256, 0, stream>>>(x, xb, w_qkv, wqkvT, w_o, woT, w1, w1T, w2, w2T);

  k_gemm<128, 0><<<dim3(QKV3 / 128, ROWS / 128), 256, 0, stream>>>(
      xb, wqkvT, ROWS, QKV3, HDIM, 1, qkvb, nullptr, nullptr, nullptr);
  k_attn<<<dim3(SEQ / 128, NHEADS, NBATCH), 512, 0, stream>>>(qkvb, mask, tau, attnb);
  k_gemm<64, 1><<<dim3(HDIM / 64, ROWS / 128), 256, 0, stream>>>(
      attnb, woT, ROWS, HDIM, HDIM, 1, x1b, x1f, x, nb1);
  k_gemm<128, 2><<<dim3(INTERDIM / 128, ROWS / 128), 256, 0, stream>>>(
      x1b, w1T, ROWS, INTERDIM, HDIM, 1, hb, nullptr, b1, nullptr);
  k_gemm<64, 3><<<dim3(HDIM / 64, ROWS / 128, 2), 256, 0, stream>>>(
      hb, w2T, ROWS, HDIM, INTERDIM, 2, nullptr, part, nullptr, nullptr);
  k_ffn2_reduce<<<ROWS * HDIM / 4 / 256, 256, 0, stream>>>(part, x1f, b2, nb2, out);
}